// Round 14
// baseline (137.155 us; speedup 1.0000x reference)
//
#include <hip/hip_runtime.h>
#include <math.h>

#define PI_F 3.14159265358979323846f
#define PI_2F 1.57079632679489662f

typedef __attribute__((ext_vector_type(8))) short short8;
typedef __attribute__((ext_vector_type(4))) float f32x4;
#define MFMA16(A,B,C) __builtin_amdgcn_mfma_f32_16x16x32_bf16(A,B,C,0,0,0)
#define SCHED_FENCE() __builtin_amdgcn_sched_barrier(0)

// ---------------- fast device math ----------------
__device__ __forceinline__ float sigm_f(float x) {
    return __fdividef(1.0f, 1.0f + __expf(-x));
}
__device__ __forceinline__ float tanh_f(float x) {
    float xc = fminf(fmaxf(x, -9.0f), 9.0f);
    float e = __expf(2.0f * xc);
    return 1.0f - __fdividef(2.0f, e + 1.0f);
}
// atan(z) for z in [0,1], max err ~1e-5 rad
__device__ __forceinline__ float atan01(float z) {
    float z2 = z * z;
    float p = fmaf(z2, -0.0117212f, 0.05265332f);
    p = fmaf(z2, p, -0.11643287f);
    p = fmaf(z2, p, 0.19354346f);
    p = fmaf(z2, p, -0.33262347f);
    p = fmaf(z2, p, 0.99997726f);
    return z * p;
}
__device__ __forceinline__ float atan_pos(float x) {
    bool big = x > 1.0f;
    float z = big ? __fdividef(1.0f, x) : x;
    float p = atan01(z);
    return big ? (PI_2F - p) : p;
}
// f32 -> bf16 (RNE) and back
__device__ __forceinline__ unsigned short f2bf(float x) {
    unsigned int u = __float_as_uint(x);
    return (unsigned short)((u + 0x7FFFu + ((u >> 16) & 1u)) >> 16);
}
__device__ __forceinline__ float bf2f(unsigned short h) {
    return __uint_as_float(((unsigned int)h) << 16);
}
__device__ __forceinline__ float lo16f(unsigned int u) { return __uint_as_float(u << 16); }
__device__ __forceinline__ float hi16f(unsigned int u) { return __uint_as_float(u & 0xFFFF0000u); }

// one Laplace series term; k = series index (sign/weight pattern period 4)
__device__ __forceinline__ float lap_term(float at, float ap, int k) {
    float th = tanh_f(at) * PI_F;
    float ph = tanh_f(ap) * (0.5f * PI_F);
    float sph = __sinf(ph), cph = __cosf(ph);
    float rdv = __fdividef(1.0f, 1.0f - sph);
    float tr = __sinf((k & 1) ? th : th + PI_2F);  // sin for odd k, cos for even
    float w = (k == 0) ? 0.5f : 1.0f;
    w = ((k + 1) & 2) ? -w : w;
    return w * tr * cph * rdv;
}

// ============================================================
// Kernel 0: pack W3 into per-(o,mt) A-fragment units:
// pk[u=(o*2+mt)][slot r=0..15][plane: th_hi|th_lo|ph_hi|ph_lo][64 shorts]
// -> in the W3 loop ONE per-lane address + imm offsets covers all
// 8 fragment loads (kills the address-register spill).
// ============================================================
__global__ __launch_bounds__(256)
void w3pack_kernel(const float* __restrict__ W3, unsigned short* __restrict__ pk)
{
    int i = blockIdx.x * 256 + threadIdx.x;   // short index
    if (i >= 34 * 4096) return;
    int u    = i >> 12;
    int rem  = i & 4095;
    int r    = rem >> 8;
    int rem2 = rem & 255;
    int pl   = rem2 >> 6;       // 0:th_hi 1:th_lo 2:ph_hi 3:ph_lo
    int s    = rem2 & 63;
    int o = u >> 1, mt = u & 1;
    int row = o * 33 + mt * 16 + r + ((pl >= 2) ? 561 : 0);
    float x = W3[row * 64 + s];
    unsigned short h = f2bf(x);
    pk[i] = (pl & 1) ? f2bf(x - bf2f(h)) : h;
}

// ============================================================
// Kernel 1: 2-layer GRU (unchanged).
// ============================================================
__global__ __launch_bounds__(128)
void gru_kernel(const float* __restrict__ act,
                const float* __restrict__ Wih0, const float* __restrict__ Whh0,
                const float* __restrict__ bih0, const float* __restrict__ bhh0,
                const float* __restrict__ Wih1, const float* __restrict__ Whh1,
                const float* __restrict__ bih1, const float* __restrict__ bhh1,
                const float* __restrict__ encW, const float* __restrict__ encb,
                float* __restrict__ p_out)
{
    __shared__ __align__(16) float wih0_l[6 * 128];
    __shared__ __align__(16) unsigned short whh0_p[16 * 32 * 8];
    __shared__ __align__(16) unsigned short wih1_p[16 * 32 * 8];
    __shared__ __align__(16) unsigned short whh1_p[16 * 32 * 8];
    __shared__ float enc_l[64];
    __shared__ __align__(16) float xbuf[4 * 32 * 6];
    __shared__ __align__(16) float hbuf0[4][32];
    __shared__ __align__(16) float hbuf1[4][32];

    const int tid = threadIdx.x;

    for (int idx = tid; idx < 96 * 6; idx += 128) {
        int r = idx / 6, c = idx - r * 6;
        wih0_l[c * 128 + (r & 31) * 4 + (r >> 5)] = Wih0[idx];
    }
    for (int idx = tid; idx < 96 * 32; idx += 128) {
        int r = idx >> 5, c = idx & 31;
        int g = r >> 5, j = r & 31;
        int d = ((c >> 1) * 32 + j) * 8 + g * 2 + (c & 1);
        whh0_p[d] = f2bf(Whh0[idx]);
        wih1_p[d] = f2bf(Wih1[idx]);
        whh1_p[d] = f2bf(Whh1[idx]);
    }
    if (tid < 64) {
        int o = tid >> 5, j = tid & 31;
        enc_l[j * 2 + o] = encW[o * 32 + j];
    }
    {
        const float inv3 = (1.0f / 3.0f);
        int base = blockIdx.x * (4 * 32 * 6);
        for (int idx = tid; idx < 4 * 32 * 6; idx += 128)
            xbuf[idx] = act[base + idx] * inv3;
    }
    __syncthreads();

    const int s = tid >> 5;
    const int j = tid & 31;
    const int b = blockIdx.x * 4 + s;
    const int j4 = j * 4;

    const float bi0r = bih0[j], bi0z = bih0[32 + j], bi0n = bih0[64 + j];
    const float bh0r = bhh0[j], bh0z = bhh0[32 + j], bh0n = bhh0[64 + j];
    const float bi1r = bih1[j], bi1z = bih1[32 + j], bi1n = bih1[64 + j];
    const float bh1r = bhh1[j], bh1z = bhh1[32 + j], bh1n = bhh1[64 + j];

    float* hb0 = &hbuf0[s][0];
    float* hb1 = &hbuf1[s][0];
    hb0[j] = 0.0f;
    hb1[j] = 0.0f;
    float h0 = 0.0f, h1 = 0.0f;
    const float* xs = &xbuf[s * 192];

    for (int t = 0; t < 32; ++t) {
        const float* xt = &xs[(31 - t) * 6];

        float ar = bi0r, az = bi0z, an = bi0n;
        #pragma unroll
        for (int d = 0; d < 6; ++d) {
            float xv = xt[d];
            const float4 w = *reinterpret_cast<const float4*>(&wih0_l[d * 128 + j4]);
            ar = fmaf(xv, w.x, ar); az = fmaf(xv, w.y, az); an = fmaf(xv, w.z, an);
        }
        {
            float gr0 = bh0r, gz0 = bh0z, gn0 = bh0n;
            float gr1 = 0.0f, gz1 = 0.0f, gn1 = 0.0f;
            #pragma unroll
            for (int ib = 0; ib < 32; ib += 4) {
                const float4 h4 = *reinterpret_cast<const float4*>(&hb0[ib]);
                const uint4 wA = *reinterpret_cast<const uint4*>(&whh0_p[((ib >> 1) * 32 + j) * 8]);
                const uint4 wB = *reinterpret_cast<const uint4*>(&whh0_p[((ib >> 1) * 32 + j + 32) * 8]);
                gr0 = fmaf(h4.x, lo16f(wA.x), gr0); gr1 = fmaf(h4.y, hi16f(wA.x), gr1);
                gz0 = fmaf(h4.x, lo16f(wA.y), gz0); gz1 = fmaf(h4.y, hi16f(wA.y), gz1);
                gn0 = fmaf(h4.x, lo16f(wA.z), gn0); gn1 = fmaf(h4.y, hi16f(wA.z), gn1);
                gr0 = fmaf(h4.z, lo16f(wB.x), gr0); gr1 = fmaf(h4.w, hi16f(wB.x), gr1);
                gz0 = fmaf(h4.z, lo16f(wB.y), gz0); gz1 = fmaf(h4.w, hi16f(wB.y), gz1);
                gn0 = fmaf(h4.z, lo16f(wB.z), gn0); gn1 = fmaf(h4.w, hi16f(wB.z), gn1);
            }
            float r = sigm_f(ar + gr0 + gr1);
            float z = sigm_f(az + gz0 + gz1);
            float n = tanh_f(an + r * (gn0 + gn1));
            h0 = (1.0f - z) * n + z * h0;
            hb0[j] = h0;
        }
        {
            float a1r0 = bi1r, a1z0 = bi1z, a1n0 = bi1n;
            float a1r1 = 0.0f, a1z1 = 0.0f, a1n1 = 0.0f;
            float g1r0 = bh1r, g1z0 = bh1z, g1n0 = bh1n;
            float g1r1 = 0.0f, g1z1 = 0.0f, g1n1 = 0.0f;
            #pragma unroll
            for (int ib = 0; ib < 32; ib += 4) {
                const float4 ha = *reinterpret_cast<const float4*>(&hb0[ib]);
                const float4 hg = *reinterpret_cast<const float4*>(&hb1[ib]);
                const uint4 aA = *reinterpret_cast<const uint4*>(&wih1_p[((ib >> 1) * 32 + j) * 8]);
                const uint4 aB = *reinterpret_cast<const uint4*>(&wih1_p[((ib >> 1) * 32 + j + 32) * 8]);
                const uint4 gA = *reinterpret_cast<const uint4*>(&whh1_p[((ib >> 1) * 32 + j) * 8]);
                const uint4 gB = *reinterpret_cast<const uint4*>(&whh1_p[((ib >> 1) * 32 + j + 32) * 8]);
                a1r0 = fmaf(ha.x, lo16f(aA.x), a1r0); a1r1 = fmaf(ha.y, hi16f(aA.x), a1r1);
                a1z0 = fmaf(ha.x, lo16f(aA.y), a1z0); a1z1 = fmaf(ha.y, hi16f(aA.y), a1z1);
                a1n0 = fmaf(ha.x, lo16f(aA.z), a1n0); a1n1 = fmaf(ha.y, hi16f(aA.z), a1n1);
                a1r0 = fmaf(ha.z, lo16f(aB.x), a1r0); a1r1 = fmaf(ha.w, hi16f(aB.x), a1r1);
                a1z0 = fmaf(ha.z, lo16f(aB.y), a1z0); a1z1 = fmaf(ha.w, hi16f(aB.y), a1z1);
                a1n0 = fmaf(ha.z, lo16f(aB.z), a1n0); a1n1 = fmaf(ha.w, hi16f(aB.z), a1n1);
                g1r0 = fmaf(hg.x, lo16f(gA.x), g1r0); g1r1 = fmaf(hg.y, hi16f(gA.x), g1r1);
                g1z0 = fmaf(hg.x, lo16f(gA.y), g1z0); g1z1 = fmaf(hg.y, hi16f(gA.y), g1z1);
                g1n0 = fmaf(hg.x, lo16f(gA.z), g1n0); g1n1 = fmaf(hg.y, hi16f(gA.z), g1n1);
                g1r0 = fmaf(hg.z, lo16f(gB.x), g1r0); g1r1 = fmaf(hg.w, hi16f(gB.x), g1r1);
                g1z0 = fmaf(hg.z, lo16f(gB.y), g1z0); g1z1 = fmaf(hg.w, hi16f(gB.y), g1z1);
                g1n0 = fmaf(hg.z, lo16f(gB.z), g1n0); g1n1 = fmaf(hg.w, hi16f(gB.z), g1n1);
            }
            float r1 = sigm_f(a1r0 + a1r1 + g1r0 + g1r1);
            float z1 = sigm_f(a1z0 + a1z1 + g1z0 + g1z1);
            float n1 = tanh_f(a1n0 + a1n1 + r1 * (g1n0 + g1n1));
            h1 = (1.0f - z1) * n1 + z1 * h1;
            hb1[j] = h1;
        }
    }

    float v0 = h1 * enc_l[j * 2 + 0];
    float v1 = h1 * enc_l[j * 2 + 1];
    #pragma unroll
    for (int off = 16; off > 0; off >>= 1) {
        v0 += __shfl_xor(v0, off, 32);
        v1 += __shfl_xor(v1, off, 32);
    }
    if (j == 0) {
        p_out[b * 2 + 0] = v0 + encb[0];
        p_out[b * 2 + 1] = v1 + encb[1];
    }
}

// ============================================================
// Kernel 2: per-(b,t) MLP + Laplace series.
// W3 A-fragments from the packed layout: ONE per-lane address per
// (o,mt) + immediate offsets 0..448 for all 8 fragments. Round-13
// fence structure kept (theta 2-group batch, phi per-group).
// ============================================================

__device__ __forceinline__ void load_B(const unsigned short* b_hi, const unsigned short* b_lo,
                                       int itm, int ksl,
                                       short8& Bh0, short8& Bh1, short8& Bl0, short8& Bl1)
{
    const int sw = (itm & 7) << 3;
    const int kx0 = ksl ^ sw;
    const int kx1 = (32 + ksl) ^ sw;
    Bh0 = *reinterpret_cast<const short8*>(&b_hi[itm * 64 + kx0]);
    Bh1 = *reinterpret_cast<const short8*>(&b_hi[itm * 64 + kx1]);
    Bl0 = *reinterpret_cast<const short8*>(&b_lo[itm * 64 + kx0]);
    Bl1 = *reinterpret_cast<const short8*>(&b_lo[itm * 64 + kx1]);
}

// epilogue for one item-group fragment: 4 series terms
__device__ __forceinline__ float lap4(f32x4 aT, f32x4 aP, const float* __restrict__ b3,
                                      int rd, int kbase)
{
    float s = 0.0f;
    #pragma unroll
    for (int r = 0; r < 4; ++r)
        s += lap_term(aT[r] + b3[rd + r], aP[r] + b3[rd + r + 561], kbase + r);
    return s;
}

// k=32 series term for one o: per-lane fp32 dot (lane = item).
__device__ __forceinline__ float k32_term(const float* __restrict__ W3f,
                                          const float* __restrict__ b3,
                                          const float* __restrict__ h2f,
                                          int o, int l4)
{
    const int rt = o * 33 + 32;
    const float* wtr = W3f + rt * 64;
    const float* wpr = W3f + (rt + 561) * 64;
    float at = b3[rt], ap = b3[rt + 561];
    #pragma unroll
    for (int c = 0; c < 16; ++c) {
        const float4 g4 = *reinterpret_cast<const float4*>(&h2f[c * 256 + l4]);
        at = fmaf(g4.x, wtr[c * 4 + 0], at);
        at = fmaf(g4.y, wtr[c * 4 + 1], at);
        at = fmaf(g4.z, wtr[c * 4 + 2], at);
        at = fmaf(g4.w, wtr[c * 4 + 3], at);
        ap = fmaf(g4.x, wpr[c * 4 + 0], ap);
        ap = fmaf(g4.y, wpr[c * 4 + 1], ap);
        ap = fmaf(g4.z, wpr[c * 4 + 2], ap);
        ap = fmaf(g4.w, wpr[c * 4 + 3], ap);
    }
    return lap_term(at, ap, 32);
}

// 6-MFMA split-bf16 accumulate of one A-stream (hi0,hi1,lo0,lo1) x one B-group
#define DOG(ACC, A0, A1, A2, A3, G) { \
    short8 Bh0, Bh1, Bl0, Bl1; \
    load_B(b_hi, b_lo, (G) * 16 + lm, ksl, Bh0, Bh1, Bl0, Bl1); \
    ACC = MFMA16(A0, Bh0, ACC); ACC = MFMA16(A1, Bh1, ACC); \
    ACC = MFMA16(A0, Bl0, ACC); ACC = MFMA16(A1, Bl1, ACC); \
    ACC = MFMA16(A2, Bh0, ACC); ACC = MFMA16(A3, Bh1, ACC); }

__global__ __launch_bounds__(512, 4)
void mlp_kernel(const float* __restrict__ obs, const float* __restrict__ ts,
                const float* __restrict__ p_act,
                const float* __restrict__ W1, const float* __restrict__ b1,
                const float* __restrict__ W2, const float* __restrict__ b2,
                const unsigned short* __restrict__ w3pk,
                const float* __restrict__ b3,
                const float* __restrict__ W3f,
                float* __restrict__ out)
{
    __shared__ __align__(16) float h1t[16 * 256];          // [i>>2][l][i&3]
    __shared__ __align__(16) unsigned short b_hi[64 * 64]; // [item][k^((item&7)<<3)]
    __shared__ __align__(16) unsigned short b_lo[64 * 64];
    __shared__ __align__(16) float vtp_lds[33 * 128];      // trig table; reused as fp32 h2
    __shared__ float f_lds[17 * 64];                       // [o][item]
    __shared__ float f16k32[64];                           // o=16 k32 terms
    __shared__ float scale_lds[64];

    float* h2f = vtp_lds;   // alias: vtp dead after H1; h2f written in H2 phase

    const int tid = threadIdx.x;
    const int wq = __builtin_amdgcn_readfirstlane(tid >> 6);  // wave id 0..7
    const int l = tid & 63;
    const int l4 = l * 4;
    const int item = blockIdx.x * 64 + l;
    const int b = item >> 4;
    const int obase = wq * 8;

    const float t = ts[item];
    const float rTc = __fdividef(0.5f, t);
    const float gamma = 0.001f + 4.6051701859880913680f * rTc;  // -ln(0.01)/Tc

    if (wq == 0) scale_lds[l] = __expf(gamma * t) * rTc;

    const float gam2 = gamma * gamma;
    const float rg = __fdividef(1.0f, gamma);
    const float pirTc = PI_F * rTc;

    // ---- trig table (once per block, k split across waves) ----
    for (int k = wq; k < 33; k += 8) {
        float sim = (float)k * pirTc;
        float vth = atan_pos(sim * rg);
        float sq = fmaf(sim, sim, gam2);
        float vph = fmaf(-2.0f, atan01(rsqrtf(sq)), PI_2F);
        vtp_lds[k * 128 + (l << 1) + 0] = vth;
        vtp_lds[k * 128 + (l << 1) + 1] = vph;
    }
    __syncthreads();

    // ---- H1: 8 outputs/wave ----
    {
        float acc[8];
        #pragma unroll
        for (int oo = 0; oo < 8; ++oo) acc[oo] = b1[obase + oo];
        const float* w1b = W1 + obase * 85;

        for (int k = 0; k < 33; ++k) {
            const float2 tp = *reinterpret_cast<const float2*>(&vtp_lds[k * 128 + (l << 1)]);
            #pragma unroll
            for (int oo = 0; oo < 8; ++oo) {
                acc[oo] = fmaf(tp.x, w1b[oo * 85 + k], acc[oo]);
                acc[oo] = fmaf(tp.y, w1b[oo * 85 + 33 + k], acc[oo]);
            }
        }
        #pragma unroll
        for (int j = 0; j < 19; ++j) {
            float pv = (j < 17) ? obs[b * 17 + j] : p_act[b * 2 + (j - 17)];
            #pragma unroll
            for (int oo = 0; oo < 8; ++oo)
                acc[oo] = fmaf(pv, w1b[oo * 85 + 66 + j], acc[oo]);
        }
        #pragma unroll
        for (int oo = 0; oo < 8; ++oo) {
            int o = obase + oo;
            h1t[(o >> 2) * 256 + l4 + (o & 3)] = tanh_f(acc[oo]);
        }
    }
    __syncthreads();   // all vtp reads done; all h1t writes done

    // ---- H2: 8 outputs/wave; bf16 hi/lo B-fragments + fp32 copy in h2f ----
    {
        float acc[8];
        #pragma unroll
        for (int oo = 0; oo < 8; ++oo) acc[oo] = b2[obase + oo];
        #pragma unroll
        for (int c = 0; c < 16; ++c) {
            const float4 g4 = *reinterpret_cast<const float4*>(&h1t[c * 256 + l4]);
            #pragma unroll
            for (int oo = 0; oo < 8; ++oo) {
                const float* wr = W2 + (obase + oo) * 64 + c * 4;
                acc[oo] = fmaf(g4.x, wr[0], acc[oo]);
                acc[oo] = fmaf(g4.y, wr[1], acc[oo]);
                acc[oo] = fmaf(g4.z, wr[2], acc[oo]);
                acc[oo] = fmaf(g4.w, wr[3], acc[oo]);
            }
        }
        const int sw = (l & 7) << 3;
        #pragma unroll
        for (int p = 0; p < 4; ++p) {
            float v0 = tanh_f(acc[2 * p + 0]);
            float v1 = tanh_f(acc[2 * p + 1]);
            int o0 = obase + 2 * p;
            h2f[((o0 + 0) >> 2) * 256 + l4 + ((o0 + 0) & 3)] = v0;
            h2f[((o0 + 1) >> 2) * 256 + l4 + ((o0 + 1) & 3)] = v1;
            unsigned short h0 = f2bf(v0), h1v = f2bf(v1);
            unsigned short q0 = f2bf(v0 - bf2f(h0)), q1 = f2bf(v1 - bf2f(h1v));
            int ksw = o0 ^ sw;
            *reinterpret_cast<unsigned int*>(&b_hi[l * 64 + ksw]) =
                (unsigned int)h0 | ((unsigned int)h1v << 16);
            *reinterpret_cast<unsigned int*>(&b_lo[l * 64 + ksw]) =
                (unsigned int)q0 | ((unsigned int)q1 << 16);
        }
    }
    __syncthreads();

    // ---- W3: packed-A single-address loads; theta 2-group batches,
    //      phi per-group immediate epilogue; sched fences ----
    {
        const int lm = l & 15;
        const int lq = l >> 4;
        const int ksl = lq * 8;
        const char* apk = (const char*)w3pk;
        const int lane_off = lm * 512 + lq * 16;   // per-lane byte offset within a unit

        #pragma unroll 1
        for (int oo2 = 0; oo2 < 2; ++oo2) {
            const int o = wq * 2 + oo2;
            const float k32t = k32_term(W3f, b3, h2f, o, l4);
            float e0 = 0.0f, e1 = 0.0f, e2 = 0.0f, e3 = 0.0f;

            #pragma unroll 1
            for (int mt = 0; mt < 2; ++mt) {
                const int n0 = o * 33 + mt * 16;
                const char* au = apk + ((o * 2 + mt) << 13) + lane_off;
                const int rd = n0 + lq * 4;
                const int kbase = mt * 16 + lq * 4;

                #pragma unroll 1
                for (int gp = 0; gp < 2; ++gp) {       // group pair: {0,1} then {2,3}
                    const int g0 = gp * 2, g1 = gp * 2 + 1;
                    f32x4 accT0 = {0,0,0,0}, accT1 = {0,0,0,0};
                    {   // theta pass — fragments from au + imm offsets
                        const short8 A0 = *reinterpret_cast<const short8*>(au + 0);
                        const short8 A1 = *reinterpret_cast<const short8*>(au + 64);
                        const short8 A2 = *reinterpret_cast<const short8*>(au + 128);
                        const short8 A3 = *reinterpret_cast<const short8*>(au + 192);
                        DOG(accT0, A0, A1, A2, A3, g0)
                        DOG(accT1, A0, A1, A2, A3, g1)
                    }
                    SCHED_FENCE();
                    {   // phi pass — per group, immediate epilogue
                        const short8 A0 = *reinterpret_cast<const short8*>(au + 256);
                        const short8 A1 = *reinterpret_cast<const short8*>(au + 320);
                        const short8 A2 = *reinterpret_cast<const short8*>(au + 384);
                        const short8 A3 = *reinterpret_cast<const short8*>(au + 448);
                        float ea, eb;
                        {
                            f32x4 accP = {0,0,0,0};
                            DOG(accP, A0, A1, A2, A3, g0)
                            ea = lap4(accT0, accP, b3, rd, kbase);
                        }
                        SCHED_FENCE();
                        {
                            f32x4 accP = {0,0,0,0};
                            DOG(accP, A0, A1, A2, A3, g1)
                            eb = lap4(accT1, accP, b3, rd, kbase);
                        }
                        if (gp == 0) { e0 += ea; e1 += eb; }
                        else         { e2 += ea; e3 += eb; }
                    }
                    SCHED_FENCE();
                }
            }
            e0 += __shfl_xor(e0, 16); e0 += __shfl_xor(e0, 32);
            e1 += __shfl_xor(e1, 16); e1 += __shfl_xor(e1, 32);
            e2 += __shfl_xor(e2, 16); e2 += __shfl_xor(e2, 32);
            e3 += __shfl_xor(e3, 16); e3 += __shfl_xor(e3, 32);
            float tot = (lq == 0) ? e0 : (lq == 1) ? e1 : (lq == 2) ? e2 : e3;
            f_lds[o * 64 + l] = tot + k32t;
        }

        // ---- o = 16: waves 0-3 one item-group each; wave 4 its k32 ----
        if (wq < 4) {
            const int g = wq;
            float facc = 0.0f;
            #pragma unroll 1
            for (int mt = 0; mt < 2; ++mt) {
                const char* au = apk + ((16 * 2 + mt) << 13) + lane_off;
                const int n0 = 16 * 33 + mt * 16;

                f32x4 aT = {0,0,0,0};
                {
                    const short8 A0 = *reinterpret_cast<const short8*>(au + 0);
                    const short8 A1 = *reinterpret_cast<const short8*>(au + 64);
                    const short8 A2 = *reinterpret_cast<const short8*>(au + 128);
                    const short8 A3 = *reinterpret_cast<const short8*>(au + 192);
                    DOG(aT, A0, A1, A2, A3, g)
                }
                SCHED_FENCE();
                f32x4 aP = {0,0,0,0};
                {
                    const short8 A0 = *reinterpret_cast<const short8*>(au + 256);
                    const short8 A1 = *reinterpret_cast<const short8*>(au + 320);
                    const short8 A2 = *reinterpret_cast<const short8*>(au + 384);
                    const short8 A3 = *reinterpret_cast<const short8*>(au + 448);
                    DOG(aP, A0, A1, A2, A3, g)
                }
                facc += lap4(aT, aP, b3, n0 + lq * 4, mt * 16 + lq * 4);
                SCHED_FENCE();
            }
            facc += __shfl_xor(facc, 16);
            facc += __shfl_xor(facc, 32);
            if (l < 16) f_lds[16 * 64 + g * 16 + l] = facc;
        } else if (wq == 4) {
            f16k32[l] = k32_term(W3f, b3, h2f, 16, l4);
        }
    }
    __syncthreads();

    // ---- scale + write out ----
    const int base_item = blockIdx.x * 64;
    for (int idx = tid; idx < 64 * 17; idx += 512) {
        const int li = idx / 17;
        const int o  = idx - li * 17;
        float v = f_lds[o * 64 + li];
        if (o == 16) v += f16k32[li];
        out[(base_item + li) * 17 + o] = v * scale_lds[li];
    }
}

extern "C" void kernel_launch(void* const* d_in, const int* in_sizes, int n_in,
                              void* d_out, int out_size, void* d_ws, size_t ws_size,
                              hipStream_t stream) {
    (void)in_sizes; (void)n_in; (void)out_size; (void)ws_size;
    const float* obs  = (const float*)d_in[0];
    const float* act  = (const float*)d_in[1];
    const float* ts   = (const float*)d_in[2];
    const float* Wih0 = (const float*)d_in[3];
    const float* Whh0 = (const float*)d_in[4];
    const float* bih0 = (const float*)d_in[5];
    const float* bhh0 = (const float*)d_in[6];
    const float* Wih1 = (const float*)d_in[7];
    const float* Whh1 = (const float*)d_in[8];
    const float* bih1 = (const float*)d_in[9];
    const float* bhh1 = (const float*)d_in[10];
    const float* encW = (const float*)d_in[11];
    const float* encb = (const float*)d_in[12];
    const float* W1   = (const float*)d_in[13];
    const float* b1   = (const float*)d_in[14];
    const float* W2   = (const float*)d_in[15];
    const float* b2   = (const float*)d_in[16];
    const float* W3   = (const float*)d_in[17];
    const float* b3   = (const float*)d_in[18];
    float* o_ptr  = (float*)d_out;

    // ws layout: p_act (16KB) | w3pk (34 * 8192 B packed A units)
    float* p_act = (float*)d_ws;
    unsigned short* w3pk = (unsigned short*)((char*)d_ws + 16384);

    w3pack_kernel<<<dim3((34 * 4096 + 255) / 256), dim3(256), 0, stream>>>(W3, w3pk);
    gru_kernel<<<dim3(512), dim3(128), 0, stream>>>(
        act, Wih0, Whh0, bih0, bhh0, Wih1, Whh1, bih1, bhh1, encW, encb, p_act);
    mlp_kernel<<<dim3(512), dim3(512), 0, stream>>>(
        obs, ts, p_act, W1, b1, W2, b2, w3pk, b3, W3, o_ptr);
}

// Round 15
// 135.742 us; speedup vs baseline: 1.0104x; 1.0104x over previous
//
#include <hip/hip_runtime.h>
#include <math.h>

#define PI_F 3.14159265358979323846f
#define PI_2F 1.57079632679489662f

typedef __attribute__((ext_vector_type(8))) short short8;
typedef __attribute__((ext_vector_type(4))) float f32x4;
#define MFMA16(A,B,C) __builtin_amdgcn_mfma_f32_16x16x32_bf16(A,B,C,0,0,0)
#define SCHED_FENCE() __builtin_amdgcn_sched_barrier(0)

// ---------------- fast device math ----------------
__device__ __forceinline__ float sigm_f(float x) {
    return __fdividef(1.0f, 1.0f + __expf(-x));
}
__device__ __forceinline__ float tanh_f(float x) {
    float xc = fminf(fmaxf(x, -9.0f), 9.0f);
    float e = __expf(2.0f * xc);
    return 1.0f - __fdividef(2.0f, e + 1.0f);
}
// atan(z) for z in [0,1], max err ~1e-5 rad
__device__ __forceinline__ float atan01(float z) {
    float z2 = z * z;
    float p = fmaf(z2, -0.0117212f, 0.05265332f);
    p = fmaf(z2, p, -0.11643287f);
    p = fmaf(z2, p, 0.19354346f);
    p = fmaf(z2, p, -0.33262347f);
    p = fmaf(z2, p, 0.99997726f);
    return z * p;
}
__device__ __forceinline__ float atan_pos(float x) {
    bool big = x > 1.0f;
    float z = big ? __fdividef(1.0f, x) : x;
    float p = atan01(z);
    return big ? (PI_2F - p) : p;
}
// f32 -> bf16 (RNE) and back
__device__ __forceinline__ unsigned short f2bf(float x) {
    unsigned int u = __float_as_uint(x);
    return (unsigned short)((u + 0x7FFFu + ((u >> 16) & 1u)) >> 16);
}
__device__ __forceinline__ float bf2f(unsigned short h) {
    return __uint_as_float(((unsigned int)h) << 16);
}
__device__ __forceinline__ float lo16f(unsigned int u) { return __uint_as_float(u << 16); }
__device__ __forceinline__ float hi16f(unsigned int u) { return __uint_as_float(u & 0xFFFF0000u); }

// one Laplace series term; k = series index (sign/weight pattern period 4)
__device__ __forceinline__ float lap_term(float at, float ap, int k) {
    float th = tanh_f(at) * PI_F;
    float ph = tanh_f(ap) * (0.5f * PI_F);
    float sph = __sinf(ph), cph = __cosf(ph);
    float rdv = __fdividef(1.0f, 1.0f - sph);
    float tr = __sinf((k & 1) ? th : th + PI_2F);  // sin for odd k, cos for even
    float w = (k == 0) ? 0.5f : 1.0f;
    w = ((k + 1) & 2) ? -w : w;
    return w * tr * cph * rdv;
}

// ============================================================
// Kernel 0: pack W3 into per-(o,mt) A-fragment units:
// pk[u=(o*2+mt)][slot r=0..15][plane: th_hi|th_lo|ph_hi|ph_lo][64 shorts]
// ============================================================
__global__ __launch_bounds__(256)
void w3pack_kernel(const float* __restrict__ W3, unsigned short* __restrict__ pk)
{
    int i = blockIdx.x * 256 + threadIdx.x;   // short index
    if (i >= 34 * 4096) return;
    int u    = i >> 12;
    int rem  = i & 4095;
    int r    = rem >> 8;
    int rem2 = rem & 255;
    int pl   = rem2 >> 6;       // 0:th_hi 1:th_lo 2:ph_hi 3:ph_lo
    int s    = rem2 & 63;
    int o = u >> 1, mt = u & 1;
    int row = o * 33 + mt * 16 + r + ((pl >= 2) ? 561 : 0);
    float x = W3[row * 64 + s];
    unsigned short h = f2bf(x);
    pk[i] = (pl & 1) ? f2bf(x - bf2f(h)) : h;
}

// ============================================================
// Kernel 1: 2-layer GRU (unchanged).
// ============================================================
__global__ __launch_bounds__(128)
void gru_kernel(const float* __restrict__ act,
                const float* __restrict__ Wih0, const float* __restrict__ Whh0,
                const float* __restrict__ bih0, const float* __restrict__ bhh0,
                const float* __restrict__ Wih1, const float* __restrict__ Whh1,
                const float* __restrict__ bih1, const float* __restrict__ bhh1,
                const float* __restrict__ encW, const float* __restrict__ encb,
                float* __restrict__ p_out)
{
    __shared__ __align__(16) float wih0_l[6 * 128];
    __shared__ __align__(16) unsigned short whh0_p[16 * 32 * 8];
    __shared__ __align__(16) unsigned short wih1_p[16 * 32 * 8];
    __shared__ __align__(16) unsigned short whh1_p[16 * 32 * 8];
    __shared__ float enc_l[64];
    __shared__ __align__(16) float xbuf[4 * 32 * 6];
    __shared__ __align__(16) float hbuf0[4][32];
    __shared__ __align__(16) float hbuf1[4][32];

    const int tid = threadIdx.x;

    for (int idx = tid; idx < 96 * 6; idx += 128) {
        int r = idx / 6, c = idx - r * 6;
        wih0_l[c * 128 + (r & 31) * 4 + (r >> 5)] = Wih0[idx];
    }
    for (int idx = tid; idx < 96 * 32; idx += 128) {
        int r = idx >> 5, c = idx & 31;
        int g = r >> 5, j = r & 31;
        int d = ((c >> 1) * 32 + j) * 8 + g * 2 + (c & 1);
        whh0_p[d] = f2bf(Whh0[idx]);
        wih1_p[d] = f2bf(Wih1[idx]);
        whh1_p[d] = f2bf(Whh1[idx]);
    }
    if (tid < 64) {
        int o = tid >> 5, j = tid & 31;
        enc_l[j * 2 + o] = encW[o * 32 + j];
    }
    {
        const float inv3 = (1.0f / 3.0f);
        int base = blockIdx.x * (4 * 32 * 6);
        for (int idx = tid; idx < 4 * 32 * 6; idx += 128)
            xbuf[idx] = act[base + idx] * inv3;
    }
    __syncthreads();

    const int s = tid >> 5;
    const int j = tid & 31;
    const int b = blockIdx.x * 4 + s;
    const int j4 = j * 4;

    const float bi0r = bih0[j], bi0z = bih0[32 + j], bi0n = bih0[64 + j];
    const float bh0r = bhh0[j], bh0z = bhh0[32 + j], bh0n = bhh0[64 + j];
    const float bi1r = bih1[j], bi1z = bih1[32 + j], bi1n = bih1[64 + j];
    const float bh1r = bhh1[j], bh1z = bhh1[32 + j], bh1n = bhh1[64 + j];

    float* hb0 = &hbuf0[s][0];
    float* hb1 = &hbuf1[s][0];
    hb0[j] = 0.0f;
    hb1[j] = 0.0f;
    float h0 = 0.0f, h1 = 0.0f;
    const float* xs = &xbuf[s * 192];

    for (int t = 0; t < 32; ++t) {
        const float* xt = &xs[(31 - t) * 6];

        float ar = bi0r, az = bi0z, an = bi0n;
        #pragma unroll
        for (int d = 0; d < 6; ++d) {
            float xv = xt[d];
            const float4 w = *reinterpret_cast<const float4*>(&wih0_l[d * 128 + j4]);
            ar = fmaf(xv, w.x, ar); az = fmaf(xv, w.y, az); an = fmaf(xv, w.z, an);
        }
        {
            float gr0 = bh0r, gz0 = bh0z, gn0 = bh0n;
            float gr1 = 0.0f, gz1 = 0.0f, gn1 = 0.0f;
            #pragma unroll
            for (int ib = 0; ib < 32; ib += 4) {
                const float4 h4 = *reinterpret_cast<const float4*>(&hb0[ib]);
                const uint4 wA = *reinterpret_cast<const uint4*>(&whh0_p[((ib >> 1) * 32 + j) * 8]);
                const uint4 wB = *reinterpret_cast<const uint4*>(&whh0_p[((ib >> 1) * 32 + j + 32) * 8]);
                gr0 = fmaf(h4.x, lo16f(wA.x), gr0); gr1 = fmaf(h4.y, hi16f(wA.x), gr1);
                gz0 = fmaf(h4.x, lo16f(wA.y), gz0); gz1 = fmaf(h4.y, hi16f(wA.y), gz1);
                gn0 = fmaf(h4.x, lo16f(wA.z), gn0); gn1 = fmaf(h4.y, hi16f(wA.z), gn1);
                gr0 = fmaf(h4.z, lo16f(wB.x), gr0); gr1 = fmaf(h4.w, hi16f(wB.x), gr1);
                gz0 = fmaf(h4.z, lo16f(wB.y), gz0); gz1 = fmaf(h4.w, hi16f(wB.y), gz1);
                gn0 = fmaf(h4.z, lo16f(wB.z), gn0); gn1 = fmaf(h4.w, hi16f(wB.z), gn1);
            }
            float r = sigm_f(ar + gr0 + gr1);
            float z = sigm_f(az + gz0 + gz1);
            float n = tanh_f(an + r * (gn0 + gn1));
            h0 = (1.0f - z) * n + z * h0;
            hb0[j] = h0;
        }
        {
            float a1r0 = bi1r, a1z0 = bi1z, a1n0 = bi1n;
            float a1r1 = 0.0f, a1z1 = 0.0f, a1n1 = 0.0f;
            float g1r0 = bh1r, g1z0 = bh1z, g1n0 = bh1n;
            float g1r1 = 0.0f, g1z1 = 0.0f, g1n1 = 0.0f;
            #pragma unroll
            for (int ib = 0; ib < 32; ib += 4) {
                const float4 ha = *reinterpret_cast<const float4*>(&hb0[ib]);
                const float4 hg = *reinterpret_cast<const float4*>(&hb1[ib]);
                const uint4 aA = *reinterpret_cast<const uint4*>(&wih1_p[((ib >> 1) * 32 + j) * 8]);
                const uint4 aB = *reinterpret_cast<const uint4*>(&wih1_p[((ib >> 1) * 32 + j + 32) * 8]);
                const uint4 gA = *reinterpret_cast<const uint4*>(&whh1_p[((ib >> 1) * 32 + j) * 8]);
                const uint4 gB = *reinterpret_cast<const uint4*>(&whh1_p[((ib >> 1) * 32 + j + 32) * 8]);
                a1r0 = fmaf(ha.x, lo16f(aA.x), a1r0); a1r1 = fmaf(ha.y, hi16f(aA.x), a1r1);
                a1z0 = fmaf(ha.x, lo16f(aA.y), a1z0); a1z1 = fmaf(ha.y, hi16f(aA.y), a1z1);
                a1n0 = fmaf(ha.x, lo16f(aA.z), a1n0); a1n1 = fmaf(ha.y, hi16f(aA.z), a1n1);
                a1r0 = fmaf(ha.z, lo16f(aB.x), a1r0); a1r1 = fmaf(ha.w, hi16f(aB.x), a1r1);
                a1z0 = fmaf(ha.z, lo16f(aB.y), a1z0); a1z1 = fmaf(ha.w, hi16f(aB.y), a1z1);
                a1n0 = fmaf(ha.z, lo16f(aB.z), a1n0); a1n1 = fmaf(ha.w, hi16f(aB.z), a1n1);
                g1r0 = fmaf(hg.x, lo16f(gA.x), g1r0); g1r1 = fmaf(hg.y, hi16f(gA.x), g1r1);
                g1z0 = fmaf(hg.x, lo16f(gA.y), g1z0); g1z1 = fmaf(hg.y, hi16f(gA.y), g1z1);
                g1n0 = fmaf(hg.x, lo16f(gA.z), g1n0); g1n1 = fmaf(hg.y, hi16f(gA.z), g1n1);
                g1r0 = fmaf(hg.z, lo16f(gB.x), g1r0); g1r1 = fmaf(hg.w, hi16f(gB.x), g1r1);
                g1z0 = fmaf(hg.z, lo16f(gB.y), g1z0); g1z1 = fmaf(hg.w, hi16f(gB.y), g1z1);
                g1n0 = fmaf(hg.z, lo16f(gB.z), g1n0); g1n1 = fmaf(hg.w, hi16f(gB.z), g1n1);
            }
            float r1 = sigm_f(a1r0 + a1r1 + g1r0 + g1r1);
            float z1 = sigm_f(a1z0 + a1z1 + g1z0 + g1z1);
            float n1 = tanh_f(a1n0 + a1n1 + r1 * (g1n0 + g1n1));
            h1 = (1.0f - z1) * n1 + z1 * h1;
            hb1[j] = h1;
        }
    }

    float v0 = h1 * enc_l[j * 2 + 0];
    float v1 = h1 * enc_l[j * 2 + 1];
    #pragma unroll
    for (int off = 16; off > 0; off >>= 1) {
        v0 += __shfl_xor(v0, off, 32);
        v1 += __shfl_xor(v1, off, 32);
    }
    if (j == 0) {
        p_out[b * 2 + 0] = v0 + encb[0];
        p_out[b * 2 + 1] = v1 + encb[1];
    }
}

// ============================================================
// Kernel 2: per-(b,t) MLP + Laplace series.
// W3 FLAT units: per (o,mt,g): load B once (shared theta+phi),
// theta A -> 6 MFMA -> accT; phi A (same reg slots) -> 6 MFMA ->
// accP; immediate epilogue into named e_g; fence. Minimal live
// window (~70 regs) -> no spill at the (512,4) 128-reg cap.
// ============================================================

__device__ __forceinline__ void load_B(const unsigned short* b_hi, const unsigned short* b_lo,
                                       int itm, int ksl,
                                       short8& Bh0, short8& Bh1, short8& Bl0, short8& Bl1)
{
    const int sw = (itm & 7) << 3;
    const int kx0 = ksl ^ sw;
    const int kx1 = (32 + ksl) ^ sw;
    Bh0 = *reinterpret_cast<const short8*>(&b_hi[itm * 64 + kx0]);
    Bh1 = *reinterpret_cast<const short8*>(&b_hi[itm * 64 + kx1]);
    Bl0 = *reinterpret_cast<const short8*>(&b_lo[itm * 64 + kx0]);
    Bl1 = *reinterpret_cast<const short8*>(&b_lo[itm * 64 + kx1]);
}

// epilogue for one item-group fragment: 4 series terms
__device__ __forceinline__ float lap4(f32x4 aT, f32x4 aP, const float* __restrict__ b3,
                                      int rd, int kbase)
{
    float s = 0.0f;
    #pragma unroll
    for (int r = 0; r < 4; ++r)
        s += lap_term(aT[r] + b3[rd + r], aP[r] + b3[rd + r + 561], kbase + r);
    return s;
}

// k=32 series term for one o: per-lane fp32 dot (lane = item).
__device__ __forceinline__ float k32_term(const float* __restrict__ W3f,
                                          const float* __restrict__ b3,
                                          const float* __restrict__ h2f,
                                          int o, int l4)
{
    const int rt = o * 33 + 32;
    const float* wtr = W3f + rt * 64;
    const float* wpr = W3f + (rt + 561) * 64;
    float at = b3[rt], ap = b3[rt + 561];
    #pragma unroll
    for (int c = 0; c < 16; ++c) {
        const float4 g4 = *reinterpret_cast<const float4*>(&h2f[c * 256 + l4]);
        at = fmaf(g4.x, wtr[c * 4 + 0], at);
        at = fmaf(g4.y, wtr[c * 4 + 1], at);
        at = fmaf(g4.z, wtr[c * 4 + 2], at);
        at = fmaf(g4.w, wtr[c * 4 + 3], at);
        ap = fmaf(g4.x, wpr[c * 4 + 0], ap);
        ap = fmaf(g4.y, wpr[c * 4 + 1], ap);
        ap = fmaf(g4.z, wpr[c * 4 + 2], ap);
        ap = fmaf(g4.w, wpr[c * 4 + 3], ap);
    }
    return lap_term(at, ap, 32);
}

// One flat W3 unit: (o,mt) A-base `au`, item-group G -> adds into EACC.
// B loaded once, shared by theta and phi passes; A regs reused.
#define UNIT_G(G, EACC) { \
    short8 Bh0, Bh1, Bl0, Bl1; \
    load_B(b_hi, b_lo, (G) * 16 + lm, ksl, Bh0, Bh1, Bl0, Bl1); \
    f32x4 accT = {0.0f, 0.0f, 0.0f, 0.0f}; \
    { \
        const short8 A0 = *reinterpret_cast<const short8*>(au + 0); \
        const short8 A1 = *reinterpret_cast<const short8*>(au + 64); \
        const short8 A2 = *reinterpret_cast<const short8*>(au + 128); \
        const short8 A3 = *reinterpret_cast<const short8*>(au + 192); \
        accT = MFMA16(A0, Bh0, accT); accT = MFMA16(A1, Bh1, accT); \
        accT = MFMA16(A0, Bl0, accT); accT = MFMA16(A1, Bl1, accT); \
        accT = MFMA16(A2, Bh0, accT); accT = MFMA16(A3, Bh1, accT); \
    } \
    f32x4 accP = {0.0f, 0.0f, 0.0f, 0.0f}; \
    { \
        const short8 A0 = *reinterpret_cast<const short8*>(au + 256); \
        const short8 A1 = *reinterpret_cast<const short8*>(au + 320); \
        const short8 A2 = *reinterpret_cast<const short8*>(au + 384); \
        const short8 A3 = *reinterpret_cast<const short8*>(au + 448); \
        accP = MFMA16(A0, Bh0, accP); accP = MFMA16(A1, Bh1, accP); \
        accP = MFMA16(A0, Bl0, accP); accP = MFMA16(A1, Bl1, accP); \
        accP = MFMA16(A2, Bh0, accP); accP = MFMA16(A3, Bh1, accP); \
    } \
    EACC += lap4(accT, accP, b3, rd, kbase); \
    SCHED_FENCE(); \
}

__global__ __launch_bounds__(512, 4)
void mlp_kernel(const float* __restrict__ obs, const float* __restrict__ ts,
                const float* __restrict__ p_act,
                const float* __restrict__ W1, const float* __restrict__ b1,
                const float* __restrict__ W2, const float* __restrict__ b2,
                const unsigned short* __restrict__ w3pk,
                const float* __restrict__ b3,
                const float* __restrict__ W3f,
                float* __restrict__ out)
{
    __shared__ __align__(16) float h1t[16 * 256];          // [i>>2][l][i&3]
    __shared__ __align__(16) unsigned short b_hi[64 * 64]; // [item][k^((item&7)<<3)]
    __shared__ __align__(16) unsigned short b_lo[64 * 64];
    __shared__ __align__(16) float vtp_lds[33 * 128];      // trig table; reused as fp32 h2
    __shared__ float f_lds[17 * 64];                       // [o][item]
    __shared__ float f16k32[64];                           // o=16 k32 terms
    __shared__ float scale_lds[64];

    float* h2f = vtp_lds;   // alias: vtp dead after H1; h2f written in H2 phase

    const int tid = threadIdx.x;
    const int wq = __builtin_amdgcn_readfirstlane(tid >> 6);  // wave id 0..7
    const int l = tid & 63;
    const int l4 = l * 4;
    const int item = blockIdx.x * 64 + l;
    const int b = item >> 4;
    const int obase = wq * 8;

    const float t = ts[item];
    const float rTc = __fdividef(0.5f, t);
    const float gamma = 0.001f + 4.6051701859880913680f * rTc;  // -ln(0.01)/Tc

    if (wq == 0) scale_lds[l] = __expf(gamma * t) * rTc;

    const float gam2 = gamma * gamma;
    const float rg = __fdividef(1.0f, gamma);
    const float pirTc = PI_F * rTc;

    // ---- trig table (once per block, k split across waves) ----
    for (int k = wq; k < 33; k += 8) {
        float sim = (float)k * pirTc;
        float vth = atan_pos(sim * rg);
        float sq = fmaf(sim, sim, gam2);
        float vph = fmaf(-2.0f, atan01(rsqrtf(sq)), PI_2F);
        vtp_lds[k * 128 + (l << 1) + 0] = vth;
        vtp_lds[k * 128 + (l << 1) + 1] = vph;
    }
    __syncthreads();

    // ---- H1: 8 outputs/wave ----
    {
        float acc[8];
        #pragma unroll
        for (int oo = 0; oo < 8; ++oo) acc[oo] = b1[obase + oo];
        const float* w1b = W1 + obase * 85;

        for (int k = 0; k < 33; ++k) {
            const float2 tp = *reinterpret_cast<const float2*>(&vtp_lds[k * 128 + (l << 1)]);
            #pragma unroll
            for (int oo = 0; oo < 8; ++oo) {
                acc[oo] = fmaf(tp.x, w1b[oo * 85 + k], acc[oo]);
                acc[oo] = fmaf(tp.y, w1b[oo * 85 + 33 + k], acc[oo]);
            }
        }
        #pragma unroll
        for (int j = 0; j < 19; ++j) {
            float pv = (j < 17) ? obs[b * 17 + j] : p_act[b * 2 + (j - 17)];
            #pragma unroll
            for (int oo = 0; oo < 8; ++oo)
                acc[oo] = fmaf(pv, w1b[oo * 85 + 66 + j], acc[oo]);
        }
        #pragma unroll
        for (int oo = 0; oo < 8; ++oo) {
            int o = obase + oo;
            h1t[(o >> 2) * 256 + l4 + (o & 3)] = tanh_f(acc[oo]);
        }
    }
    __syncthreads();   // all vtp reads done; all h1t writes done

    // ---- H2: 8 outputs/wave; bf16 hi/lo B-fragments + fp32 copy in h2f ----
    {
        float acc[8];
        #pragma unroll
        for (int oo = 0; oo < 8; ++oo) acc[oo] = b2[obase + oo];
        #pragma unroll
        for (int c = 0; c < 16; ++c) {
            const float4 g4 = *reinterpret_cast<const float4*>(&h1t[c * 256 + l4]);
            #pragma unroll
            for (int oo = 0; oo < 8; ++oo) {
                const float* wr = W2 + (obase + oo) * 64 + c * 4;
                acc[oo] = fmaf(g4.x, wr[0], acc[oo]);
                acc[oo] = fmaf(g4.y, wr[1], acc[oo]);
                acc[oo] = fmaf(g4.z, wr[2], acc[oo]);
                acc[oo] = fmaf(g4.w, wr[3], acc[oo]);
            }
        }
        const int sw = (l & 7) << 3;
        #pragma unroll
        for (int p = 0; p < 4; ++p) {
            float v0 = tanh_f(acc[2 * p + 0]);
            float v1 = tanh_f(acc[2 * p + 1]);
            int o0 = obase + 2 * p;
            h2f[((o0 + 0) >> 2) * 256 + l4 + ((o0 + 0) & 3)] = v0;
            h2f[((o0 + 1) >> 2) * 256 + l4 + ((o0 + 1) & 3)] = v1;
            unsigned short h0 = f2bf(v0), h1v = f2bf(v1);
            unsigned short q0 = f2bf(v0 - bf2f(h0)), q1 = f2bf(v1 - bf2f(h1v));
            int ksw = o0 ^ sw;
            *reinterpret_cast<unsigned int*>(&b_hi[l * 64 + ksw]) =
                (unsigned int)h0 | ((unsigned int)h1v << 16);
            *reinterpret_cast<unsigned int*>(&b_lo[l * 64 + ksw]) =
                (unsigned int)q0 | ((unsigned int)q1 << 16);
        }
    }
    __syncthreads();

    // ---- W3: flat (o,mt,g) units; minimal live window ----
    {
        const int lm = l & 15;
        const int lq = l >> 4;
        const int ksl = lq * 8;
        const char* apk = (const char*)w3pk;
        const int lane_off = lm * 512 + lq * 16;   // per-lane byte offset within a unit

        #pragma unroll 1
        for (int oo2 = 0; oo2 < 2; ++oo2) {
            const int o = wq * 2 + oo2;
            const float k32t = k32_term(W3f, b3, h2f, o, l4);
            float e0 = 0.0f, e1 = 0.0f, e2 = 0.0f, e3 = 0.0f;

            #pragma unroll 1
            for (int mt = 0; mt < 2; ++mt) {
                const char* au = apk + ((o * 2 + mt) << 13) + lane_off;
                const int rd = o * 33 + mt * 16 + lq * 4;
                const int kbase = mt * 16 + lq * 4;

                UNIT_G(0, e0)
                UNIT_G(1, e1)
                UNIT_G(2, e2)
                UNIT_G(3, e3)
            }
            e0 += __shfl_xor(e0, 16); e0 += __shfl_xor(e0, 32);
            e1 += __shfl_xor(e1, 16); e1 += __shfl_xor(e1, 32);
            e2 += __shfl_xor(e2, 16); e2 += __shfl_xor(e2, 32);
            e3 += __shfl_xor(e3, 16); e3 += __shfl_xor(e3, 32);
            float tot = (lq == 0) ? e0 : (lq == 1) ? e1 : (lq == 2) ? e2 : e3;
            f_lds[o * 64 + l] = tot + k32t;
        }

        // ---- o = 16: waves 0-3 one item-group each; wave 4 its k32 ----
        if (wq < 4) {
            const int g = wq;
            float facc = 0.0f;
            #pragma unroll 1
            for (int mt = 0; mt < 2; ++mt) {
                const char* au = apk + ((16 * 2 + mt) << 13) + lane_off;
                const int rd = 16 * 33 + mt * 16 + lq * 4;
                const int kbase = mt * 16 + lq * 4;
                UNIT_G(g, facc)
            }
            facc += __shfl_xor(facc, 16);
            facc += __shfl_xor(facc, 32);
            if (l < 16) f_lds[16 * 64 + g * 16 + l] = facc;
        } else if (wq == 4) {
            f16k32[l] = k32_term(W3f, b3, h2f, 16, l4);
        }
    }
    __syncthreads();

    // ---- scale + write out ----
    const int base_item = blockIdx.x * 64;
    for (int idx = tid; idx < 64 * 17; idx += 512) {
        const int li = idx / 17;
        const int o  = idx - li * 17;
        float v = f_lds[o * 64 + li];
        if (o == 16) v += f16k32[li];
        out[(base_item + li) * 17 + o] = v * scale_lds[li];
    }
}

extern "C" void kernel_launch(void* const* d_in, const int* in_sizes, int n_in,
                              void* d_out, int out_size, void* d_ws, size_t ws_size,
                              hipStream_t stream) {
    (void)in_sizes; (void)n_in; (void)out_size; (void)ws_size;
    const float* obs  = (const float*)d_in[0];
    const float* act  = (const float*)d_in[1];
    const float* ts   = (const float*)d_in[2];
    const float* Wih0 = (const float*)d_in[3];
    const float* Whh0 = (const float*)d_in[4];
    const float* bih0 = (const float*)d_in[5];
    const float* bhh0 = (const float*)d_in[6];
    const float* Wih1 = (const float*)d_in[7];
    const float* Whh1 = (const float*)d_in[8];
    const float* bih1 = (const float*)d_in[9];
    const float* bhh1 = (const float*)d_in[10];
    const float* encW = (const float*)d_in[11];
    const float* encb = (const float*)d_in[12];
    const float* W1   = (const float*)d_in[13];
    const float* b1   = (const float*)d_in[14];
    const float* W2   = (const float*)d_in[15];
    const float* b2   = (const float*)d_in[16];
    const float* W3   = (const float*)d_in[17];
    const float* b3   = (const float*)d_in[18];
    float* o_ptr  = (float*)d_out;

    // ws layout: p_act (16KB) | w3pk (34 * 8192 B packed A units)
    float* p_act = (float*)d_ws;
    unsigned short* w3pk = (unsigned short*)((char*)d_ws + 16384);

    w3pack_kernel<<<dim3((34 * 4096 + 255) / 256), dim3(256), 0, stream>>>(W3, w3pk);
    gru_kernel<<<dim3(512), dim3(128), 0, stream>>>(
        act, Wih0, Whh0, bih0, bhh0, Wih1, Whh1, bih1, bhh1, encW, encb, p_act);
    mlp_kernel<<<dim3(512), dim3(512), 0, stream>>>(
        obs, ts, p_act, W1, b1, W2, b2, w3pk, b3, W3, o_ptr);
}

// Round 16
// 116.561 us; speedup vs baseline: 1.1767x; 1.1646x over previous
//
#include <hip/hip_runtime.h>
#include <math.h>

#define PI_F 3.14159265358979323846f
#define PI_2F 1.57079632679489662f

typedef __attribute__((ext_vector_type(8))) short short8;
typedef __attribute__((ext_vector_type(4))) float f32x4;
#define MFMA16(A,B,C) __builtin_amdgcn_mfma_f32_16x16x32_bf16(A,B,C,0,0,0)
#define SCHED_FENCE() __builtin_amdgcn_sched_barrier(0)

// ---------------- fast device math ----------------
__device__ __forceinline__ float sigm_f(float x) {
    return __fdividef(1.0f, 1.0f + __expf(-x));
}
__device__ __forceinline__ float tanh_f(float x) {
    float xc = fminf(fmaxf(x, -9.0f), 9.0f);
    float e = __expf(2.0f * xc);
    return 1.0f - __fdividef(2.0f, e + 1.0f);
}
// atan(z) for z in [0,1], max err ~1e-5 rad
__device__ __forceinline__ float atan01(float z) {
    float z2 = z * z;
    float p = fmaf(z2, -0.0117212f, 0.05265332f);
    p = fmaf(z2, p, -0.11643287f);
    p = fmaf(z2, p, 0.19354346f);
    p = fmaf(z2, p, -0.33262347f);
    p = fmaf(z2, p, 0.99997726f);
    return z * p;
}
__device__ __forceinline__ float atan_pos(float x) {
    bool big = x > 1.0f;
    float z = big ? __fdividef(1.0f, x) : x;
    float p = atan01(z);
    return big ? (PI_2F - p) : p;
}
// f32 -> bf16 (RNE) and back
__device__ __forceinline__ unsigned short f2bf(float x) {
    unsigned int u = __float_as_uint(x);
    return (unsigned short)((u + 0x7FFFu + ((u >> 16) & 1u)) >> 16);
}
__device__ __forceinline__ float bf2f(unsigned short h) {
    return __uint_as_float(((unsigned int)h) << 16);
}
__device__ __forceinline__ float lo16f(unsigned int u) { return __uint_as_float(u << 16); }
__device__ __forceinline__ float hi16f(unsigned int u) { return __uint_as_float(u & 0xFFFF0000u); }

// one Laplace series term; k = series index (sign/weight pattern period 4)
__device__ __forceinline__ float lap_term(float at, float ap, int k) {
    float th = tanh_f(at) * PI_F;
    float ph = tanh_f(ap) * (0.5f * PI_F);
    float sph = __sinf(ph), cph = __cosf(ph);
    float rdv = __fdividef(1.0f, 1.0f - sph);
    float tr = __sinf((k & 1) ? th : th + PI_2F);  // sin for odd k, cos for even
    float w = (k == 0) ? 0.5f : 1.0f;
    w = ((k + 1) & 2) ? -w : w;
    return w * tr * cph * rdv;
}

// ============================================================
// Kernel 0: pack W3 into per-(o,mt) A-fragment units:
// pk[u=(o*2+mt)][slot r=0..15][plane: th_hi|th_lo|ph_hi|ph_lo][64 shorts]
// ============================================================
__global__ __launch_bounds__(256)
void w3pack_kernel(const float* __restrict__ W3, unsigned short* __restrict__ pk)
{
    int i = blockIdx.x * 256 + threadIdx.x;   // short index
    if (i >= 34 * 4096) return;
    int u    = i >> 12;
    int rem  = i & 4095;
    int r    = rem >> 8;
    int rem2 = rem & 255;
    int pl   = rem2 >> 6;       // 0:th_hi 1:th_lo 2:ph_hi 3:ph_lo
    int s    = rem2 & 63;
    int o = u >> 1, mt = u & 1;
    int row = o * 33 + mt * 16 + r + ((pl >= 2) ? 561 : 0);
    float x = W3[row * 64 + s];
    unsigned short h = f2bf(x);
    pk[i] = (pl & 1) ? f2bf(x - bf2f(h)) : h;
}

// ============================================================
// Kernel 1: 2-layer GRU, 256 threads = 4 samples, ONE sample/wave.
// Lane (j = l&31, half = l>>5): each half accumulates its 16-input
// slice of every gate matvec; halves combined via __shfl_xor(·,32).
// Halves serial FMA depth per step and doubles wave count (2048).
// n-gate input/recurrent parts kept separate (PyTorch semantics).
// ============================================================
__global__ __launch_bounds__(256)
void gru_kernel(const float* __restrict__ act,
                const float* __restrict__ Wih0, const float* __restrict__ Whh0,
                const float* __restrict__ bih0, const float* __restrict__ bhh0,
                const float* __restrict__ Wih1, const float* __restrict__ Whh1,
                const float* __restrict__ bih1, const float* __restrict__ bhh1,
                const float* __restrict__ encW, const float* __restrict__ encb,
                float* __restrict__ p_out)
{
    __shared__ __align__(16) float wih0_l[6 * 128];
    __shared__ __align__(16) unsigned short whh0_p[16 * 32 * 8];
    __shared__ __align__(16) unsigned short wih1_p[16 * 32 * 8];
    __shared__ __align__(16) unsigned short whh1_p[16 * 32 * 8];
    __shared__ float enc_l[64];
    __shared__ __align__(16) float xbuf[4 * 32 * 6];
    __shared__ __align__(16) float hbuf0[4][32];
    __shared__ __align__(16) float hbuf1[4][32];

    const int tid = threadIdx.x;

    for (int idx = tid; idx < 96 * 6; idx += 256) {
        int r = idx / 6, c = idx - r * 6;
        wih0_l[c * 128 + (r & 31) * 4 + (r >> 5)] = Wih0[idx];
    }
    for (int idx = tid; idx < 96 * 32; idx += 256) {
        int r = idx >> 5, c = idx & 31;     // r = gate*32 + j_out, c = input idx
        int g = r >> 5, j = r & 31;
        int d = ((c >> 1) * 32 + j) * 8 + g * 2 + (c & 1);
        whh0_p[d] = f2bf(Whh0[idx]);
        wih1_p[d] = f2bf(Wih1[idx]);
        whh1_p[d] = f2bf(Whh1[idx]);
    }
    if (tid < 64) {
        int o = tid >> 5, j = tid & 31;
        enc_l[j * 2 + o] = encW[o * 32 + j];
    }
    {
        const float inv3 = (1.0f / 3.0f);
        int base = blockIdx.x * (4 * 32 * 6);
        for (int idx = tid; idx < 4 * 32 * 6; idx += 256)
            xbuf[idx] = act[base + idx] * inv3;
    }
    __syncthreads();

    const int s = tid >> 6;       // sample = wave
    const int l = tid & 63;
    const int j = l & 31;
    const int half = l >> 5;      // i-range half
    const int i0 = half * 16;
    const int sb = half * 8;      // slot base (2 inputs per slot)
    const int j4 = j * 4;
    const int b = blockIdx.x * 4 + s;
    const float z0f = (half == 0) ? 1.0f : 0.0f;

    // biases: contribute once (half 0)
    const float bi0r = z0f * bih0[j], bi0z = z0f * bih0[32 + j], bi0n = z0f * bih0[64 + j];
    const float bh0r = z0f * bhh0[j], bh0z = z0f * bhh0[32 + j], bh0n = z0f * bhh0[64 + j];
    const float bi1r = z0f * bih1[j], bi1z = z0f * bih1[32 + j], bi1n = z0f * bih1[64 + j];
    const float bh1r = z0f * bhh1[j], bh1z = z0f * bhh1[32 + j], bh1n = z0f * bhh1[64 + j];

    float* hb0 = &hbuf0[s][0];
    float* hb1 = &hbuf1[s][0];
    if (!half) { hb0[j] = 0.0f; hb1[j] = 0.0f; }
    float h0 = 0.0f, h1 = 0.0f;
    const float* xs = &xbuf[s * 192];

    for (int t = 0; t < 32; ++t) {
        const float* xt = &xs[(31 - t) * 6];

        // ---- layer 0 ----
        // chains: R/Z fold input+rec (legal: summed inside sigmoid);
        // N split: an = x-side, gn = rec-side (n = tanh(an + r*gn)).
        float gr0 = bi0r + bh0r, gz0 = bi0z + bh0z, gn0 = bh0n, an = bi0n;
        if (half == 0) {
            #pragma unroll
            for (int d = 0; d < 6; ++d) {
                float xv = xt[d];
                const float4 w = *reinterpret_cast<const float4*>(&wih0_l[d * 128 + j4]);
                gr0 = fmaf(xv, w.x, gr0); gz0 = fmaf(xv, w.y, gz0); an = fmaf(xv, w.z, an);
            }
        }
        {
            float gr1 = 0.0f, gz1 = 0.0f, gn1 = 0.0f;
            #pragma unroll
            for (int m = 0; m < 8; m += 2) {
                const float2 ha = *reinterpret_cast<const float2*>(&hb0[i0 + 2 * m]);
                const float2 hc = *reinterpret_cast<const float2*>(&hb0[i0 + 2 * m + 2]);
                const uint4 wA = *reinterpret_cast<const uint4*>(&whh0_p[((sb + m) * 32 + j) * 8]);
                const uint4 wB = *reinterpret_cast<const uint4*>(&whh0_p[((sb + m + 1) * 32 + j) * 8]);
                gr0 = fmaf(ha.x, lo16f(wA.x), gr0); gr0 = fmaf(ha.y, hi16f(wA.x), gr0);
                gz0 = fmaf(ha.x, lo16f(wA.y), gz0); gz0 = fmaf(ha.y, hi16f(wA.y), gz0);
                gn0 = fmaf(ha.x, lo16f(wA.z), gn0); gn0 = fmaf(ha.y, hi16f(wA.z), gn0);
                gr1 = fmaf(hc.x, lo16f(wB.x), gr1); gr1 = fmaf(hc.y, hi16f(wB.x), gr1);
                gz1 = fmaf(hc.x, lo16f(wB.y), gz1); gz1 = fmaf(hc.y, hi16f(wB.y), gz1);
                gn1 = fmaf(hc.x, lo16f(wB.z), gn1); gn1 = fmaf(hc.y, hi16f(wB.z), gn1);
            }
            float grt = gr0 + gr1; grt += __shfl_xor(grt, 32);
            float gzt = gz0 + gz1; gzt += __shfl_xor(gzt, 32);
            float gnt = gn0 + gn1; gnt += __shfl_xor(gnt, 32);
            float ant = an;        ant += __shfl_xor(ant, 32);
            float r = sigm_f(grt);
            float z = sigm_f(gzt);
            float n = tanh_f(ant + r * gnt);
            h0 = (1.0f - z) * n + z * h0;     // identical in both halves
            if (!half) hb0[j] = h0;
        }

        // ---- layer 1: input side (h0-new) + rec side (h1-old) ----
        {
            float R0 = bi1r + bh1r, Z0 = bi1z + bh1z, aN0 = bi1n, gN0 = bh1n;
            float R1 = 0.0f, Z1 = 0.0f, aN1 = 0.0f, gN1 = 0.0f;
            #pragma unroll
            for (int m = 0; m < 8; m += 2) {
                const float2 ha = *reinterpret_cast<const float2*>(&hb0[i0 + 2 * m]);
                const float2 hc = *reinterpret_cast<const float2*>(&hb0[i0 + 2 * m + 2]);
                const float2 pa = *reinterpret_cast<const float2*>(&hb1[i0 + 2 * m]);
                const float2 pc = *reinterpret_cast<const float2*>(&hb1[i0 + 2 * m + 2]);
                const uint4 aA = *reinterpret_cast<const uint4*>(&wih1_p[((sb + m) * 32 + j) * 8]);
                const uint4 aB = *reinterpret_cast<const uint4*>(&wih1_p[((sb + m + 1) * 32 + j) * 8]);
                const uint4 gA = *reinterpret_cast<const uint4*>(&whh1_p[((sb + m) * 32 + j) * 8]);
                const uint4 gB = *reinterpret_cast<const uint4*>(&whh1_p[((sb + m + 1) * 32 + j) * 8]);
                R0 = fmaf(ha.x, lo16f(aA.x), R0); R0 = fmaf(ha.y, hi16f(aA.x), R0);
                Z0 = fmaf(ha.x, lo16f(aA.y), Z0); Z0 = fmaf(ha.y, hi16f(aA.y), Z0);
                aN0 = fmaf(ha.x, lo16f(aA.z), aN0); aN0 = fmaf(ha.y, hi16f(aA.z), aN0);
                R1 = fmaf(hc.x, lo16f(aB.x), R1); R1 = fmaf(hc.y, hi16f(aB.x), R1);
                Z1 = fmaf(hc.x, lo16f(aB.y), Z1); Z1 = fmaf(hc.y, hi16f(aB.y), Z1);
                aN1 = fmaf(hc.x, lo16f(aB.z), aN1); aN1 = fmaf(hc.y, hi16f(aB.z), aN1);
                R0 = fmaf(pa.x, lo16f(gA.x), R0); R0 = fmaf(pa.y, hi16f(gA.x), R0);
                Z0 = fmaf(pa.x, lo16f(gA.y), Z0); Z0 = fmaf(pa.y, hi16f(gA.y), Z0);
                gN0 = fmaf(pa.x, lo16f(gA.z), gN0); gN0 = fmaf(pa.y, hi16f(gA.z), gN0);
                R1 = fmaf(pc.x, lo16f(gB.x), R1); R1 = fmaf(pc.y, hi16f(gB.x), R1);
                Z1 = fmaf(pc.x, lo16f(gB.y), Z1); Z1 = fmaf(pc.y, hi16f(gB.y), Z1);
                gN1 = fmaf(pc.x, lo16f(gB.z), gN1); gN1 = fmaf(pc.y, hi16f(gB.z), gN1);
            }
            float Rt = R0 + R1;   Rt += __shfl_xor(Rt, 32);
            float Zt = Z0 + Z1;   Zt += __shfl_xor(Zt, 32);
            float aNt = aN0 + aN1; aNt += __shfl_xor(aNt, 32);
            float gNt = gN0 + gN1; gNt += __shfl_xor(gNt, 32);
            float r1 = sigm_f(Rt);
            float z1 = sigm_f(Zt);
            float n1 = tanh_f(aNt + r1 * gNt);
            h1 = (1.0f - z1) * n1 + z1 * h1;
            if (!half) hb1[j] = h1;
        }
    }

    // encoder head (h1 identical in both halves; reduce within 32 lanes)
    float v0 = h1 * enc_l[j * 2 + 0];
    float v1 = h1 * enc_l[j * 2 + 1];
    #pragma unroll
    for (int off = 16; off > 0; off >>= 1) {
        v0 += __shfl_xor(v0, off, 32);
        v1 += __shfl_xor(v1, off, 32);
    }
    if (l == 0) {
        p_out[b * 2 + 0] = v0 + encb[0];
        p_out[b * 2 + 1] = v1 + encb[1];
    }
}

// ============================================================
// Kernel 2: per-(b,t) MLP + Laplace series.
// W3 flat (o,mt,g) units; B-lo plane DROPPED (cross-term Whi*hlo
// rms ~1e-3 on at/ap, negligible vs threshold): 4 MFMA/acc, B=8
// regs, -8KB LDS, -30% W3 LDS reads + register relief vs spill.
// ============================================================

__device__ __forceinline__ void load_B(const unsigned short* b_hi,
                                       int itm, int ksl, short8& Bh0, short8& Bh1)
{
    const int sw = (itm & 7) << 3;
    Bh0 = *reinterpret_cast<const short8*>(&b_hi[itm * 64 + (ksl ^ sw)]);
    Bh1 = *reinterpret_cast<const short8*>(&b_hi[itm * 64 + ((32 + ksl) ^ sw)]);
}

// epilogue for one item-group fragment: 4 series terms
__device__ __forceinline__ float lap4(f32x4 aT, f32x4 aP, const float* __restrict__ b3,
                                      int rd, int kbase)
{
    float s = 0.0f;
    #pragma unroll
    for (int r = 0; r < 4; ++r)
        s += lap_term(aT[r] + b3[rd + r], aP[r] + b3[rd + r + 561], kbase + r);
    return s;
}

// k=32 series term for one o: per-lane fp32 dot (lane = item).
__device__ __forceinline__ float k32_term(const float* __restrict__ W3f,
                                          const float* __restrict__ b3,
                                          const float* __restrict__ h2f,
                                          int o, int l4)
{
    const int rt = o * 33 + 32;
    const float* wtr = W3f + rt * 64;
    const float* wpr = W3f + (rt + 561) * 64;
    float at = b3[rt], ap = b3[rt + 561];
    #pragma unroll
    for (int c = 0; c < 16; ++c) {
        const float4 g4 = *reinterpret_cast<const float4*>(&h2f[c * 256 + l4]);
        at = fmaf(g4.x, wtr[c * 4 + 0], at);
        at = fmaf(g4.y, wtr[c * 4 + 1], at);
        at = fmaf(g4.z, wtr[c * 4 + 2], at);
        at = fmaf(g4.w, wtr[c * 4 + 3], at);
        ap = fmaf(g4.x, wpr[c * 4 + 0], ap);
        ap = fmaf(g4.y, wpr[c * 4 + 1], ap);
        ap = fmaf(g4.z, wpr[c * 4 + 2], ap);
        ap = fmaf(g4.w, wpr[c * 4 + 3], ap);
    }
    return lap_term(at, ap, 32);
}

// One flat W3 unit: (o,mt) A-base `au`, item-group G -> adds into EACC.
// 4 MFMA per acc: Ahi*Bhi (k0,k1) + Alo*Bhi (k0,k1).
#define UNIT_G(G, EACC) { \
    short8 Bh0, Bh1; \
    load_B(b_hi, (G) * 16 + lm, ksl, Bh0, Bh1); \
    f32x4 accT = {0.0f, 0.0f, 0.0f, 0.0f}; \
    { \
        const short8 A0 = *reinterpret_cast<const short8*>(au + 0); \
        const short8 A1 = *reinterpret_cast<const short8*>(au + 64); \
        const short8 A2 = *reinterpret_cast<const short8*>(au + 128); \
        const short8 A3 = *reinterpret_cast<const short8*>(au + 192); \
        accT = MFMA16(A0, Bh0, accT); accT = MFMA16(A1, Bh1, accT); \
        accT = MFMA16(A2, Bh0, accT); accT = MFMA16(A3, Bh1, accT); \
    } \
    f32x4 accP = {0.0f, 0.0f, 0.0f, 0.0f}; \
    { \
        const short8 A0 = *reinterpret_cast<const short8*>(au + 256); \
        const short8 A1 = *reinterpret_cast<const short8*>(au + 320); \
        const short8 A2 = *reinterpret_cast<const short8*>(au + 384); \
        const short8 A3 = *reinterpret_cast<const short8*>(au + 448); \
        accP = MFMA16(A0, Bh0, accP); accP = MFMA16(A1, Bh1, accP); \
        accP = MFMA16(A2, Bh0, accP); accP = MFMA16(A3, Bh1, accP); \
    } \
    EACC += lap4(accT, accP, b3, rd, kbase); \
    SCHED_FENCE(); \
}

__global__ __launch_bounds__(512, 4)
void mlp_kernel(const float* __restrict__ obs, const float* __restrict__ ts,
                const float* __restrict__ p_act,
                const float* __restrict__ W1, const float* __restrict__ b1,
                const float* __restrict__ W2, const float* __restrict__ b2,
                const unsigned short* __restrict__ w3pk,
                const float* __restrict__ b3,
                const float* __restrict__ W3f,
                float* __restrict__ out)
{
    __shared__ __align__(16) float h1t[16 * 256];          // [i>>2][l][i&3]
    __shared__ __align__(16) unsigned short b_hi[64 * 64]; // [item][k^((item&7)<<3)]
    __shared__ __align__(16) float vtp_lds[33 * 128];      // trig table; reused as fp32 h2
    __shared__ float f_lds[17 * 64];                       // [o][item]
    __shared__ float f16k32[64];                           // o=16 k32 terms
    __shared__ float scale_lds[64];

    float* h2f = vtp_lds;   // alias: vtp dead after H1; h2f written in H2 phase

    const int tid = threadIdx.x;
    const int wq = __builtin_amdgcn_readfirstlane(tid >> 6);  // wave id 0..7
    const int l = tid & 63;
    const int l4 = l * 4;
    const int item = blockIdx.x * 64 + l;
    const int b = item >> 4;
    const int obase = wq * 8;

    const float t = ts[item];
    const float rTc = __fdividef(0.5f, t);
    const float gamma = 0.001f + 4.6051701859880913680f * rTc;  // -ln(0.01)/Tc

    if (wq == 0) scale_lds[l] = __expf(gamma * t) * rTc;

    const float gam2 = gamma * gamma;
    const float rg = __fdividef(1.0f, gamma);
    const float pirTc = PI_F * rTc;

    // ---- trig table (once per block, k split across waves) ----
    for (int k = wq; k < 33; k += 8) {
        float sim = (float)k * pirTc;
        float vth = atan_pos(sim * rg);
        float sq = fmaf(sim, sim, gam2);
        float vph = fmaf(-2.0f, atan01(rsqrtf(sq)), PI_2F);
        vtp_lds[k * 128 + (l << 1) + 0] = vth;
        vtp_lds[k * 128 + (l << 1) + 1] = vph;
    }
    __syncthreads();

    // ---- H1: 8 outputs/wave ----
    {
        float acc[8];
        #pragma unroll
        for (int oo = 0; oo < 8; ++oo) acc[oo] = b1[obase + oo];
        const float* w1b = W1 + obase * 85;

        for (int k = 0; k < 33; ++k) {
            const float2 tp = *reinterpret_cast<const float2*>(&vtp_lds[k * 128 + (l << 1)]);
            #pragma unroll
            for (int oo = 0; oo < 8; ++oo) {
                acc[oo] = fmaf(tp.x, w1b[oo * 85 + k], acc[oo]);
                acc[oo] = fmaf(tp.y, w1b[oo * 85 + 33 + k], acc[oo]);
            }
        }
        #pragma unroll
        for (int j = 0; j < 19; ++j) {
            float pv = (j < 17) ? obs[b * 17 + j] : p_act[b * 2 + (j - 17)];
            #pragma unroll
            for (int oo = 0; oo < 8; ++oo)
                acc[oo] = fmaf(pv, w1b[oo * 85 + 66 + j], acc[oo]);
        }
        #pragma unroll
        for (int oo = 0; oo < 8; ++oo) {
            int o = obase + oo;
            h1t[(o >> 2) * 256 + l4 + (o & 3)] = tanh_f(acc[oo]);
        }
    }
    __syncthreads();   // all vtp reads done; all h1t writes done

    // ---- H2: 8 outputs/wave; bf16 hi B-fragments + fp32 copy in h2f ----
    {
        float acc[8];
        #pragma unroll
        for (int oo = 0; oo < 8; ++oo) acc[oo] = b2[obase + oo];
        #pragma unroll
        for (int c = 0; c < 16; ++c) {
            const float4 g4 = *reinterpret_cast<const float4*>(&h1t[c * 256 + l4]);
            #pragma unroll
            for (int oo = 0; oo < 8; ++oo) {
                const float* wr = W2 + (obase + oo) * 64 + c * 4;
                acc[oo] = fmaf(g4.x, wr[0], acc[oo]);
                acc[oo] = fmaf(g4.y, wr[1], acc[oo]);
                acc[oo] = fmaf(g4.z, wr[2], acc[oo]);
                acc[oo] = fmaf(g4.w, wr[3], acc[oo]);
            }
        }
        const int sw = (l & 7) << 3;
        #pragma unroll
        for (int p = 0; p < 4; ++p) {
            float v0 = tanh_f(acc[2 * p + 0]);
            float v1 = tanh_f(acc[2 * p + 1]);
            int o0 = obase + 2 * p;
            h2f[((o0 + 0) >> 2) * 256 + l4 + ((o0 + 0) & 3)] = v0;
            h2f[((o0 + 1) >> 2) * 256 + l4 + ((o0 + 1) & 3)] = v1;
            unsigned short h0 = f2bf(v0), h1v = f2bf(v1);
            int ksw = o0 ^ sw;
            *reinterpret_cast<unsigned int*>(&b_hi[l * 64 + ksw]) =
                (unsigned int)h0 | ((unsigned int)h1v << 16);
        }
    }
    __syncthreads();

    // ---- W3: flat (o,mt,g) units ----
    {
        const int lm = l & 15;
        const int lq = l >> 4;
        const int ksl = lq * 8;
        const char* apk = (const char*)w3pk;
        const int lane_off = lm * 512 + lq * 16;   // per-lane byte offset within a unit

        #pragma unroll 1
        for (int oo2 = 0; oo2 < 2; ++oo2) {
            const int o = wq * 2 + oo2;
            const float k32t = k32_term(W3f, b3, h2f, o, l4);
            float e0 = 0.0f, e1 = 0.0f, e2 = 0.0f, e3 = 0.0f;

            #pragma unroll 1
            for (int mt = 0; mt < 2; ++mt) {
                const char* au = apk + ((o * 2 + mt) << 13) + lane_off;
                const int rd = o * 33 + mt * 16 + lq * 4;
                const int kbase = mt * 16 + lq * 4;

                UNIT_G(0, e0)
                UNIT_G(1, e1)
                UNIT_G(2, e2)
                UNIT_G(3, e3)
            }
            e0 += __shfl_xor(e0, 16); e0 += __shfl_xor(e0, 32);
            e1 += __shfl_xor(e1, 16); e1 += __shfl_xor(e1, 32);
            e2 += __shfl_xor(e2, 16); e2 += __shfl_xor(e2, 32);
            e3 += __shfl_xor(e3, 16); e3 += __shfl_xor(e3, 32);
            float tot = (lq == 0) ? e0 : (lq == 1) ? e1 : (lq == 2) ? e2 : e3;
            f_lds[o * 64 + l] = tot + k32t;
        }

        // ---- o = 16: waves 0-3 one item-group each; wave 4 its k32 ----
        if (wq < 4) {
            const int g = wq;
            float facc = 0.0f;
            #pragma unroll 1
            for (int mt = 0; mt < 2; ++mt) {
                const char* au = apk + ((16 * 2 + mt) << 13) + lane_off;
                const int rd = 16 * 33 + mt * 16 + lq * 4;
                const int kbase = mt * 16 + lq * 4;
                UNIT_G(g, facc)
            }
            facc += __shfl_xor(facc, 16);
            facc += __shfl_xor(facc, 32);
            if (l < 16) f_lds[16 * 64 + g * 16 + l] = facc;
        } else if (wq == 4) {
            f16k32[l] = k32_term(W3f, b3, h2f, 16, l4);
        }
    }
    __syncthreads();

    // ---- scale + write out ----
    const int base_item = blockIdx.x * 64;
    for (int idx = tid; idx < 64 * 17; idx += 512) {
        const int li = idx / 17;
        const int o  = idx - li * 17;
        float v = f_lds[o * 64 + li];
        if (o == 16) v += f16k32[li];
        out[(base_item + li) * 17 + o] = v * scale_lds[li];
    }
}

extern "C" void kernel_launch(void* const* d_in, const int* in_sizes, int n_in,
                              void* d_out, int out_size, void* d_ws, size_t ws_size,
                              hipStream_t stream) {
    (void)in_sizes; (void)n_in; (void)out_size; (void)ws_size;
    const float* obs  = (const float*)d_in[0];
    const float* act  = (const float*)d_in[1];
    const float* ts   = (const float*)d_in[2];
    const float* Wih0 = (const float*)d_in[3];
    const float* Whh0 = (const float*)d_in[4];
    const float* bih0 = (const float*)d_in[5];
    const float* bhh0 = (const float*)d_in[6];
    const float* Wih1 = (const float*)d_in[7];
    const float* Whh1 = (const float*)d_in[8];
    const float* bih1 = (const float*)d_in[9];
    const float* bhh1 = (const float*)d_in[10];
    const float* encW = (const float*)d_in[11];
    const float* encb = (const float*)d_in[12];
    const float* W1   = (const float*)d_in[13];
    const float* b1   = (const float*)d_in[14];
    const float* W2   = (const float*)d_in[15];
    const float* b2   = (const float*)d_in[16];
    const float* W3   = (const float*)d_in[17];
    const float* b3   = (const float*)d_in[18];
    float* o_ptr  = (float*)d_out;

    // ws layout: p_act (16KB) | w3pk (34 * 8192 B packed A units)
    float* p_act = (float*)d_ws;
    unsigned short* w3pk = (unsigned short*)((char*)d_ws + 16384);

    w3pack_kernel<<<dim3((34 * 4096 + 255) / 256), dim3(256), 0, stream>>>(W3, w3pk);
    gru_kernel<<<dim3(512), dim3(256), 0, stream>>>(
        act, Wih0, Whh0, bih0, bhh0, Wih1, Whh1, bih1, bhh1, encW, encb, p_act);
    mlp_kernel<<<dim3(512), dim3(512), 0, stream>>>(
        obs, ts, p_act, W1, b1, W2, b2, w3pk, b3, W3, o_ptr);
}